// Round 3
// baseline (375.717 us; speedup 1.0000x reference)
//
#include <hip/hip_runtime.h>
#include <hip/hip_bf16.h>
#include <math.h>

typedef __hip_bfloat16 bf16;
typedef short short8 __attribute__((ext_vector_type(8)));
typedef float floatx4 __attribute__((ext_vector_type(4)));

#define NB 16
#define NC 256
#define NHW 1024
#define NNE 256
#define NP (NB*NC*NHW)

__device__ __forceinline__ unsigned short f2bu(float f){
  bf16 h = (bf16)f; return *(unsigned short*)&h;
}

// ---------------- GroupNorm two-pass (+Swish) -> packed bf16 x_p[b][cc][px][32] ----------------
template<bool SWISH>
__global__ void gn_t_kernel(const float* __restrict__ src, const float* __restrict__ gamma,
                            const float* __restrict__ beta, short* __restrict__ xp){
  int b = blockIdx.x >> 5, g = blockIdx.x & 31;
  const int GSZ = 8*NHW;
  size_t base = ((size_t)b*NC + g*8)*NHW;
  int tid = threadIdx.x;
  float s = 0.f, ss = 0.f;
  for (int i = tid; i < GSZ; i += 256){
    float v = src[base+i];
    s += v; ss += v*v;
  }
  __shared__ float rs[256], rq[256];
  rs[tid] = s; rq[tid] = ss;
  __syncthreads();
  for (int off=128; off>0; off>>=1){
    if (tid < off){ rs[tid]+=rs[tid+off]; rq[tid]+=rq[tid+off]; }
    __syncthreads();
  }
  float mean = rs[0] * (1.f/GSZ);
  float var  = rq[0] * (1.f/GSZ) - mean*mean;
  float inv  = rsqrtf(var + 1e-5f);
  float gm[8], bt[8];
  #pragma unroll
  for (int j=0;j<8;j++){ gm[j] = gamma[g*8+j]*inv; bt[j] = beta[g*8+j]; }
  short* dst = xp + (((size_t)b*8 + (g>>2))*NHW)*32 + (g&3)*8;
  for (int px = tid; px < NHW; px += 256){
    short8 pk;
    #pragma unroll
    for (int j=0;j<8;j++){
      float v = (src[base + j*NHW + px] - mean)*gm[j] + bt[j];
      if (SWISH) v = v / (1.f + __expf(-v));
      pk[j] = (short)f2bu(v);
    }
    *(short8*)(dst + (size_t)px*32) = pk;
  }
}

// ---------------- GroupNorm single-pass from precomputed stats ----------------
template<bool SWISH>
__global__ void gn_post_kernel(const float* __restrict__ src, const float* __restrict__ st,
                               const float* __restrict__ gamma, const float* __restrict__ beta,
                               short* __restrict__ xp){
  int b = blockIdx.x >> 5, g = blockIdx.x & 31;
  size_t base = ((size_t)b*NC + g*8)*NHW;
  int tid = threadIdx.x;
  float s  = st[(b*32+g)*2+0];
  float ss = st[(b*32+g)*2+1];
  float mean = s * (1.f/8192.f);
  float var  = ss * (1.f/8192.f) - mean*mean;
  float inv  = rsqrtf(var + 1e-5f);
  float gm[8], bt[8];
  #pragma unroll
  for (int j=0;j<8;j++){ gm[j] = gamma[g*8+j]*inv; bt[j] = beta[g*8+j]; }
  short* dst = xp + (((size_t)b*8 + (g>>2))*NHW)*32 + (g&3)*8;
  for (int px = tid; px < NHW; px += 256){
    short8 pk;
    #pragma unroll
    for (int j=0;j<8;j++){
      float v = (src[base + j*NHW + px] - mean)*gm[j] + bt[j];
      if (SWISH) v = v / (1.f + __expf(-v));
      pk[j] = (short)f2bu(v);
    }
    *(short8*)(dst + (size_t)px*32) = pk;
  }
}

// ---------------- conv3 weight prep + stats zero ----------------
__global__ void wprep3_kernel(const float* __restrict__ w1, const float* __restrict__ w2,
                              short* __restrict__ wp1, short* __restrict__ wp2,
                              float* __restrict__ st){
  int co = blockIdx.x & 255;
  const float* w = (blockIdx.x < 256) ? w1 : w2;
  short* wp = (blockIdx.x < 256) ? wp1 : wp2;
  int tid = threadIdx.x;
  if (blockIdx.x == 0){
    for (int i=tid;i<2048;i+=256) st[i] = 0.f;
  }
  __shared__ float tmp[2304];
  for (int i=tid;i<2304;i+=256) tmp[i] = w[(size_t)co*2304 + i];   // [ci][tap]
  __syncthreads();
  for (int j=tid;j<2304;j+=256){
    int tap = j>>8, ci = j&255;
    wp[(((size_t)tap*8 + (ci>>5))*NC + co)*32 + (ci&31)] = (short)f2bu(tmp[ci*9 + tap]);
  }
}

// ---------------- 1x1 weight prep: qkv(768) + cfunc(256) + outw(256) ----------------
__global__ void wprep1_kernel(const float* __restrict__ wq, const float* __restrict__ wc,
                              const float* __restrict__ wo,
                              short* __restrict__ wqp, short* __restrict__ wcp,
                              short* __restrict__ wop){
  int blk = blockIdx.x, tid = threadIdx.x;
  if (blk < 768){
    float v = wq[(size_t)blk*256 + tid];
    wqp[(((size_t)(tid>>5))*768 + blk)*32 + (tid&31)] = (short)f2bu(v);
  } else if (blk < 1024){
    int co = blk - 768;
    float v = wc[(size_t)co*256 + tid];
    wcp[(((size_t)(tid>>5))*256 + co)*32 + (tid&31)] = (short)f2bu(v);
  } else {
    int co = blk - 1024;
    float v = wo[(size_t)co*256 + tid];
    wop[(((size_t)(tid>>5))*256 + co)*32 + (tid&31)] = (short)f2bu(v);
  }
}

// ---------------- c_in fp32 [b][ci][hw] -> cp[b][cc][px][32] bf16 ----------------
__global__ void cvtc_kernel(const float* __restrict__ c_in, short* __restrict__ cp){
  int pxc = blockIdx.x, cc = blockIdx.y, b = blockIdx.z, tid = threadIdx.x;
  __shared__ float ld[32][257];
  size_t gbase = ((size_t)b*NC + cc*32)*NHW + pxc*256;
  for (int j=0;j<32;j++) ld[j][tid] = c_in[gbase + (size_t)j*NHW + tid];
  __syncthreads();
  short* dst = cp + (((size_t)b*8 + cc)*NHW + pxc*256)*32;
  for (int it=0;it<4;it++){
    int pxl = it*64 + (tid>>2), ckl = tid&3;
    short8 pk;
    #pragma unroll
    for (int e=0;e<8;e++) pk[e] = (short)f2bu(ld[ckl*8+e][pxl]);
    *(short8*)(dst + (size_t)pxl*32 + ckl*8) = pk;
  }
}

// ---------------- FeatureWiseAffine bias: na[b][c] ----------------
__global__ void noise_kernel(const float* __restrict__ emb, const float* __restrict__ w,
                             const float* __restrict__ bias, float* __restrict__ na){
  int b = blockIdx.x, c = threadIdx.x;
  __shared__ float e[NNE];
  e[c] = emb[b*NNE + c];
  __syncthreads();
  float acc = bias[c];
  for (int k=0;k<NNE;k++) acc += e[k]*w[c*NNE+k];
  na[b*NC + c] = acc;
}

// ---------------- MFMA conv3x3: 1 output row/block, 512 blocks, 2 blocks/CU ----------------
// Occupancy fix vs 2-row version: grid 256->512 (2 blocks/CU, 2 waves/SIMD via
// launch_bounds(256,2)); Xs 72KB->54KB so 2 blocks fit LDS. Staging index remapped so
// lanes 0-15 write 16 consecutive 16B chunks (conflict-free ds_write).
#define XSTR 264
__global__ __launch_bounds__(256,2)
void conv3_mfma_kernel(const short* __restrict__ xp, const short* __restrict__ wp,
                       const float* __restrict__ bias, const float* __restrict__ bias_bc,
                       const float* __restrict__ addf, float* __restrict__ out,
                       float* __restrict__ st){
  const int b = blockIdx.y, y0 = blockIdx.x;
  const int tid = threadIdx.x, wave = tid>>6, lane = tid&63;
  const int quad = lane>>4, lm = lane&15;
  __shared__ short Xs[3*34*XSTR];      // rows y0-1..y0+1, 53856 B

  if (tid < 192){ // zero halo columns: 3 rows x 2 sides x 32 chunks
    int r = tid>>6, side = (tid>>5)&1, ck = tid&31;
    short8 z = {0,0,0,0,0,0,0,0};
    *(short8*)&Xs[((r*34) + side*33)*XSTR + ck*8] = z;
  }
  for (int it=0; it<12; ++it){
    int idx = it*256 + tid;
    int r = idx>>10, rem = idx&1023;
    int x = rem>>5, ch = rem&31;       // lanes 0-15 -> consecutive 16B chunks of one (r,x)
    int y = y0 - 1 + r;
    short8 v = {0,0,0,0,0,0,0,0};
    if ((unsigned)y < 32u)
      v = *(const short8*)(xp + (((size_t)b*8 + (ch>>2))*NHW + y*32 + x)*32 + (ch&3)*8);
    *(short8*)&Xs[(r*34 + x + 1)*XSTR + ch*8] = v;
  }
  __syncthreads();

  floatx4 acc[4][2];
  #pragma unroll
  for (int mt=0;mt<4;mt++)
    #pragma unroll
    for (int nt=0;nt<2;nt++) acc[mt][nt] = (floatx4){0.f,0.f,0.f,0.f};

  const int co_w = wave*64;
  const int aoff = (co_w + lm)*32 + quad*8;

  auto ldA = [&](int j, short8 a[4]){
    const short* p = wp + (size_t)j*NC*32 + aoff;
    #pragma unroll
    for (int mt=0;mt<4;mt++) a[mt] = *(const short8*)(p + mt*(16*32));
  };
  auto ldB = [&](int j, short8 bf[2]){
    int tap = j>>3, kk = j&7;
    int dy = (tap*11)>>5;
    int dxp = tap - dy*3;
    int base = (lm+dxp)*XSTR + quad*8 + kk*32 + dy*(34*XSTR);
    #pragma unroll
    for (int nt=0;nt<2;nt++)
      bf[nt] = *(const short8*)&Xs[base + nt*(16*XSTR)];
  };

  short8 A[4][4], Bf[4][2];
  ldA(0,A[0]); ldB(0,Bf[0]);
  ldA(1,A[1]); ldB(1,Bf[1]);
  ldA(2,A[2]); ldB(2,Bf[2]);
  ldA(3,A[3]); ldB(3,Bf[3]);
  for (int it=0; it<72; it+=4){
    #pragma unroll
    for (int u=0;u<4;u++){
      #pragma unroll
      for (int mt=0;mt<4;mt++)
        #pragma unroll
        for (int nt=0;nt<2;nt++)
          acc[mt][nt] = __builtin_amdgcn_mfma_f32_16x16x32_bf16(A[u][mt], Bf[u][nt], acc[mt][nt], 0,0,0);
      int j = it + 4 + u; if (j > 71) j = 71;
      ldA(j, A[u]); ldB(j, Bf[u]);
    }
  }

  const int hw0 = y0*32;
  float gs[4], gq[4];
  #pragma unroll
  for (int mt=0;mt<4;mt++){ gs[mt]=0.f; gq[mt]=0.f; }
  #pragma unroll
  for (int mt=0;mt<4;mt++){
    #pragma unroll
    for (int r=0;r<4;r++){
      int co = co_w + mt*16 + quad*4 + r;
      float bb = bias[co] + (bias_bc ? bias_bc[b*NC + co] : 0.f);
      size_t ob = ((size_t)b*NC + co)*NHW + hw0;
      #pragma unroll
      for (int nt=0;nt<2;nt++){
        size_t oi = ob + nt*16 + lm;
        float v = acc[mt][nt][r] + bb;
        if (addf) v += addf[oi];
        out[oi] = v;
        gs[mt] += v; gq[mt] += v*v;
      }
    }
  }
  #pragma unroll
  for (int mt=0;mt<4;mt++){
    float s = gs[mt], q = gq[mt];
    #pragma unroll
    for (int o=1;o<32;o<<=1){ s += __shfl_xor(s, o, 64); q += __shfl_xor(q, o, 64); }
    if ((lane&31) == 0){
      int g = (co_w>>3) + mt*2 + (quad>>1);
      atomicAdd(&st[(b*32+g)*2+0], s);
      atomicAdd(&st[(b*32+g)*2+1], q);
    }
  }
}

// ---------------- MFMA GEMM: cfunc(c) + bias + x -> fp32 [b][co][hw] ----------------
__global__ __launch_bounds__(256)
void gemm_cfunc_kernel(const short* __restrict__ cp, const short* __restrict__ wcp,
                       const float* __restrict__ bias, const float* __restrict__ xres,
                       float* __restrict__ out){
  const int b = blockIdx.z;
  const int tid = threadIdx.x, wave = tid>>6, lane = tid&63;
  const int quad = lane>>4, lm = lane&15;
  const int M0 = blockIdx.y*128 + (wave>>1)*64;
  const int N0 = blockIdx.x*128 + (wave&1)*64;
  floatx4 acc[4][4];
  #pragma unroll
  for (int mt=0;mt<4;mt++)
    #pragma unroll
    for (int nt=0;nt<4;nt++) acc[mt][nt] = (floatx4){0.f,0.f,0.f,0.f};
  #pragma unroll
  for (int kk=0;kk<8;kk++){
    short8 af[4], bfr[4];
    #pragma unroll
    for (int mt=0;mt<4;mt++)
      af[mt] = *(const short8*)(wcp + ((size_t)kk*256 + M0 + mt*16 + lm)*32 + quad*8);
    #pragma unroll
    for (int nt=0;nt<4;nt++)
      bfr[nt] = *(const short8*)(cp + (((size_t)b*8 + kk)*NHW + N0 + nt*16 + lm)*32 + quad*8);
    #pragma unroll
    for (int mt=0;mt<4;mt++)
      #pragma unroll
      for (int nt=0;nt<4;nt++)
        acc[mt][nt] = __builtin_amdgcn_mfma_f32_16x16x32_bf16(af[mt], bfr[nt], acc[mt][nt], 0,0,0);
  }
  #pragma unroll
  for (int mt=0;mt<4;mt++){
    #pragma unroll
    for (int r=0;r<4;r++){
      int co = M0 + mt*16 + quad*4 + r;
      float bb = bias[co];
      size_t ob = ((size_t)b*NC + co)*NHW + N0;
      #pragma unroll
      for (int nt=0;nt<4;nt++){
        size_t oi = ob + nt*16 + lm;
        out[oi] = acc[mt][nt][r] + bb + xres[oi];
      }
    }
  }
}

// ---------------- MFMA GEMM qkv ----------------
__global__ __launch_bounds__(256)
void gemm_qkv_kernel(const short* __restrict__ ntp, const short* __restrict__ wqp,
                     short* __restrict__ qp, short* __restrict__ kp, short* __restrict__ vp){
  const int b = blockIdx.z;
  const int tid = threadIdx.x, wave = tid>>6, lane = tid&63;
  const int quad = lane>>4, lm = lane&15;
  const int M0 = blockIdx.y*128 + (wave>>1)*64;
  const int N0 = blockIdx.x*128 + (wave&1)*64;
  floatx4 acc[4][4];
  #pragma unroll
  for (int mt=0;mt<4;mt++)
    #pragma unroll
    for (int nt=0;nt<4;nt++) acc[mt][nt] = (floatx4){0.f,0.f,0.f,0.f};
  #pragma unroll
  for (int kk=0;kk<8;kk++){
    short8 af[4], bfr[4];
    #pragma unroll
    for (int mt=0;mt<4;mt++)
      af[mt] = *(const short8*)(wqp + ((size_t)kk*768 + M0 + mt*16 + lm)*32 + quad*8);
    #pragma unroll
    for (int nt=0;nt<4;nt++)
      bfr[nt] = *(const short8*)(ntp + (((size_t)b*8 + kk)*NHW + N0 + nt*16 + lm)*32 + quad*8);
    #pragma unroll
    for (int mt=0;mt<4;mt++)
      #pragma unroll
      for (int nt=0;nt<4;nt++)
        acc[mt][nt] = __builtin_amdgcn_mfma_f32_16x16x32_bf16(af[mt], bfr[nt], acc[mt][nt], 0,0,0);
  }
  #pragma unroll
  for (int mt=0;mt<4;mt++){
    int co_base = M0 + mt*16 + quad*4;
    int sec = co_base >> 8;
    int c = co_base & 255;
    #pragma unroll
    for (int nt=0;nt<4;nt++){
      int s = N0 + nt*16 + lm;
      if (sec < 2){
        unsigned short t0 = f2bu(acc[mt][nt][0]), t1 = f2bu(acc[mt][nt][1]);
        unsigned short t2 = f2bu(acc[mt][nt][2]), t3 = f2bu(acc[mt][nt][3]);
        uint2 w2; w2.x = ((unsigned)t1<<16)|t0; w2.y = ((unsigned)t3<<16)|t2;
        short* dst = (sec==0) ? qp : kp;
        *(uint2*)(dst + (((size_t)b*8 + (c>>5))*NHW + s)*32 + (c&31)) = w2;
      } else {
        #pragma unroll
        for (int r=0;r<4;r++)
          vp[(((size_t)b*32 + (s>>5))*NC + c + r)*32 + (s&31)] = (short)f2bu(acc[mt][nt][r]);
      }
    }
  }
}

// ---------------- MFMA fused attention: 64 q-rows/block, 16 waves, 256 blocks ----------------
__global__ __launch_bounds__(1024)
void attn_mfma_kernel(const short* __restrict__ qp, const short* __restrict__ kp,
                      const short* __restrict__ vp, short* __restrict__ op){
  const int bx = blockIdx.x;
  const int b = bx & 15;               // XCD pin: batches {b,b+8} -> XCD b&7 (32 blocks/XCD)
  const int s0 = (bx >> 4) * 64;
  const int tid = threadIdx.x, wave = tid>>6, lane = tid&63;
  const int quad = lane>>4, lm = lane&15;

  __shared__ short P[64*1024];         // 128 KB, XOR-swizzled granules
  __shared__ float red[64][16];        // reused for max then sum
  __shared__ float fred[64];           // reused for row-max then 1/row-sum

  // ---- phase 1: S = Q K^T ; wave covers rows[0..64) x cols[wave*64 .. +64) ----
  floatx4 sc[4][4];
  #pragma unroll
  for (int rt=0;rt<4;rt++)
    #pragma unroll
    for (int ti=0;ti<4;ti++) sc[rt][ti] = (floatx4){0.f,0.f,0.f,0.f};

  const int colb = wave*64;
  #pragma unroll
  for (int h=0;h<8;h++){
    const size_t hb = ((size_t)b*8 + h)*NHW;
    short8 aq[4], kf[4];
    #pragma unroll
    for (int rt=0;rt<4;rt++)
      aq[rt] = *(const short8*)(qp + (hb + s0 + rt*16 + lm)*32 + quad*8);
    #pragma unroll
    for (int ti=0;ti<4;ti++)
      kf[ti] = *(const short8*)(kp + (hb + colb + ti*16 + lm)*32 + quad*8);
    #pragma unroll
    for (int rt=0;rt<4;rt++)
      #pragma unroll
      for (int ti=0;ti<4;ti++)
        sc[rt][ti] = __builtin_amdgcn_mfma_f32_16x16x32_bf16(aq[rt], kf[ti], sc[rt][ti], 0,0,0);
  }

  // ---- softmax over rows (cols split across 16 waves) ----
  const float scale = 0.0625f;
  float mx[4][4];
  #pragma unroll
  for (int rt=0;rt<4;rt++)
    #pragma unroll
    for (int r=0;r<4;r++) mx[rt][r] = -1e30f;
  #pragma unroll
  for (int rt=0;rt<4;rt++)
    #pragma unroll
    for (int ti=0;ti<4;ti++)
      #pragma unroll
      for (int r=0;r<4;r++){
        float v = sc[rt][ti][r]*scale;
        sc[rt][ti][r] = v;
        mx[rt][r] = fmaxf(mx[rt][r], v);
      }
  #pragma unroll
  for (int o=1;o<16;o<<=1)
    #pragma unroll
    for (int rt=0;rt<4;rt++)
      #pragma unroll
      for (int r=0;r<4;r++) mx[rt][r] = fmaxf(mx[rt][r], __shfl_xor(mx[rt][r], o, 64));
  if (lm==0){
    #pragma unroll
    for (int rt=0;rt<4;rt++)
      #pragma unroll
      for (int r=0;r<4;r++) red[rt*16 + quad*4 + r][wave] = mx[rt][r];
  }
  __syncthreads();
  { // stage-2 max: 16 threads per row
    float v = red[tid>>4][tid&15];
    #pragma unroll
    for (int o=1;o<16;o<<=1) v = fmaxf(v, __shfl_xor(v, o, 64));
    if ((tid&15)==0) fred[tid>>4] = v;
  }
  __syncthreads();
  float fmr[4][4], sm[4][4];
  #pragma unroll
  for (int rt=0;rt<4;rt++)
    #pragma unroll
    for (int r=0;r<4;r++){ fmr[rt][r] = fred[rt*16 + quad*4 + r]; sm[rt][r] = 0.f; }
  #pragma unroll
  for (int rt=0;rt<4;rt++)
    #pragma unroll
    for (int ti=0;ti<4;ti++)
      #pragma unroll
      for (int r=0;r<4;r++){
        float e = __expf(sc[rt][ti][r] - fmr[rt][r]);
        sc[rt][ti][r] = e;
        sm[rt][r] += e;
      }
  #pragma unroll
  for (int o=1;o<16;o<<=1)
    #pragma unroll
    for (int rt=0;rt<4;rt++)
      #pragma unroll
      for (int r=0;r<4;r++) sm[rt][r] += __shfl_xor(sm[rt][r], o, 64);
  __syncthreads();   // red[] (max partials) dead -> safe to reuse for sums
  if (lm==0){
    #pragma unroll
    for (int rt=0;rt<4;rt++)
      #pragma unroll
      for (int r=0;r<4;r++) red[rt*16 + quad*4 + r][wave] = sm[rt][r];
  }
  __syncthreads();
  { // stage-2 sum -> 1/sum
    float v = red[tid>>4][tid&15];
    #pragma unroll
    for (int o=1;o<16;o<<=1) v += __shfl_xor(v, o, 64);
    if ((tid&15)==0) fred[tid>>4] = 1.f/v;
  }
  __syncthreads();
  float fir[4][4];
  #pragma unroll
  for (int rt=0;rt<4;rt++)
    #pragma unroll
    for (int r=0;r<4;r++) fir[rt][r] = fred[rt*16 + quad*4 + r];
  // write P normalized, swizzled: elem(row,col) at row*1024 + ((col>>3 ^ row&7)<<3) + (col&7)
  #pragma unroll
  for (int rt=0;rt<4;rt++)
    #pragma unroll
    for (int ti=0;ti<4;ti++)
      #pragma unroll
      for (int r=0;r<4;r++){
        int row = rt*16 + quad*4 + r;
        int col = colb + ti*16 + lm;
        int off = row*1024 + ((((col>>3) ^ (row&7))&127)<<3) + (col&7);
        P[off] = (short)f2bu(sc[rt][ti][r]*fir[rt][r]);
      }
  __syncthreads();

  // ---- phase 2: O = P V^T ; wave = (cg: 32 ch, sh: 32 s) ----
  const int cg = wave>>1, sh = wave&1;
  const int ch0 = cg*32;
  floatx4 oacc[2][2];
  #pragma unroll
  for (int mt=0;mt<2;mt++)
    #pragma unroll
    for (int nt=0;nt<2;nt++) oacc[mt][nt] = (floatx4){0.f,0.f,0.f,0.f};

  #pragma unroll
  for (int kk=0;kk<32;kk++){
    short8 pf[2], vf[2];
    #pragma unroll
    for (int mt=0;mt<2;mt++){
      int row = sh*32 + mt*16 + lm;
      int off = row*1024 + ((((kk*4 + quad) ^ (row&7))&127)<<3);
      pf[mt] = *(const short8*)(&P[off]);
    }
    #pragma unroll
    for (int nt=0;nt<2;nt++)
      vf[nt] = *(const short8*)(vp + (((size_t)b*32 + kk)*NC + ch0 + nt*16 + lm)*32 + quad*8);
    #pragma unroll
    for (int mt=0;mt<2;mt++)
      #pragma unroll
      for (int nt=0;nt<2;nt++)
        oacc[mt][nt] = __builtin_amdgcn_mfma_f32_16x16x32_bf16(pf[mt], vf[nt], oacc[mt][nt], 0,0,0);
  }

  // packed bf16 epilogue: o_p[b][cc][s][32]
  #pragma unroll
  for (int nt=0;nt<2;nt++){
    int c = ch0 + nt*16 + lm;
    int cc = c>>5, cl = c&31;
    #pragma unroll
    for (int mt=0;mt<2;mt++)
      #pragma unroll
      for (int r=0;r<4;r++){
        int s = s0 + sh*32 + mt*16 + quad*4 + r;
        op[(((size_t)b*8 + cc)*NHW + s)*32 + cl] = (short)f2bu(oacc[mt][nt][r]);
      }
  }
}

// ---------------- MFMA out-proj: out = W@o + out_b + h ----------------
__global__ __launch_bounds__(256)
void outproj_mfma_kernel(const short* __restrict__ op, const short* __restrict__ wop,
                         const float* __restrict__ obias, const float* __restrict__ h,
                         float* __restrict__ out){
  const int b = blockIdx.z;
  const int tid = threadIdx.x, wave = tid>>6, lane = tid&63;
  const int quad = lane>>4, lm = lane&15;
  const int M0 = blockIdx.y*128 + (wave>>1)*64;
  const int N0 = blockIdx.x*128 + (wave&1)*64;
  floatx4 acc[4][4];
  #pragma unroll
  for (int mt=0;mt<4;mt++)
    #pragma unroll
    for (int nt=0;nt<4;nt++) acc[mt][nt] = (floatx4){0.f,0.f,0.f,0.f};
  #pragma unroll
  for (int kk=0;kk<8;kk++){
    short8 af[4], bfr[4];
    #pragma unroll
    for (int mt=0;mt<4;mt++)
      af[mt] = *(const short8*)(wop + ((size_t)kk*256 + M0 + mt*16 + lm)*32 + quad*8);
    #pragma unroll
    for (int nt=0;nt<4;nt++)
      bfr[nt] = *(const short8*)(op + (((size_t)b*8 + kk)*NHW + N0 + nt*16 + lm)*32 + quad*8);
    #pragma unroll
    for (int mt=0;mt<4;mt++)
      #pragma unroll
      for (int nt=0;nt<4;nt++)
        acc[mt][nt] = __builtin_amdgcn_mfma_f32_16x16x32_bf16(af[mt], bfr[nt], acc[mt][nt], 0,0,0);
  }
  #pragma unroll
  for (int mt=0;mt<4;mt++){
    #pragma unroll
    for (int r=0;r<4;r++){
      int co = M0 + mt*16 + quad*4 + r;
      float bb = obias[co];
      size_t ob = ((size_t)b*NC + co)*NHW + N0;
      #pragma unroll
      for (int nt=0;nt<4;nt++){
        size_t oi = ob + nt*16 + lm;
        out[oi] = acc[mt][nt][r] + bb + h[oi];
      }
    }
  }
}

extern "C" void kernel_launch(void* const* d_in, const int* in_sizes, int n_in,
                              void* d_out, int out_size, void* d_ws, size_t ws_size,
                              hipStream_t stream){
  const float* x        = (const float*)d_in[0];
  const float* time_emb = (const float*)d_in[1];
  const float* c_in     = (const float*)d_in[2];
  const float* gn1_g    = (const float*)d_in[3];
  const float* gn1_b    = (const float*)d_in[4];
  const float* conv1_w  = (const float*)d_in[5];
  const float* conv1_b  = (const float*)d_in[6];
  const float* noise_w  = (const float*)d_in[7];
  const float* noise_b  = (const float*)d_in[8];
  const float* gn2_g    = (const float*)d_in[9];
  const float* gn2_b    = (const float*)d_in[10];
  const float* conv2_w  = (const float*)d_in[11];
  const float* conv2_b  = (const float*)d_in[12];
  const float* cfunc_w  = (const float*)d_in[13];
  const float* cfunc_b  = (const float*)d_in[14];
  const float* agn_g    = (const float*)d_in[15];
  const float* agn_b    = (const float*)d_in[16];
  const float* qkv_w    = (const float*)d_in[17];
  const float* out_w    = (const float*)d_in[18];
  const float* out_b    = (const float*)d_in[19];
  float* outp = (float*)d_out;

  // ---- workspace layout (~67 MB) ----
  float* ws = (float*)d_ws;
  float* buf_h = ws;                       // NP fp32
  float* buf_t = buf_h + NP;               // NP fp32 (early: cp bf16 alias; late: o_p bf16 alias)
  short* xpb   = (short*)(buf_t + NP);     // NP bf16
  short* qp    = xpb + NP;                 // NP bf16
  short* kp    = qp + NP;                  // NP bf16
  short* vp    = kp + NP;                  // NP bf16
  short* wp1   = vp + NP;                  // 589824
  short* wp2   = wp1 + 589824;             // 589824
  short* wqp   = wp2 + 589824;             // 196608
  short* wcp   = wqp + 196608;             // 65536
  short* wop   = wcp + 65536;              // 65536
  float* na    = (float*)(wop + 65536);    // NB*NC
  float* st    = na + NB*NC;               // 2048 floats
  float* st2   = st;
  float* st3   = st + 1024;
  short* cp    = (short*)buf_t;            // alias (dead after gemm_cfunc)
  short* op    = (short*)buf_t;            // alias (written by attn after cp dead)

  // ---- prep ----
  wprep3_kernel<<<512, 256, 0, stream>>>(conv1_w, conv2_w, wp1, wp2, st);
  wprep1_kernel<<<1280, 256, 0, stream>>>(qkv_w, cfunc_w, out_w, wqp, wcp, wop);
  cvtc_kernel<<<dim3(4,8,NB), 256, 0, stream>>>(c_in, cp);
  noise_kernel<<<NB, 256, 0, stream>>>(time_emb, noise_w, noise_b, na);
  // ---- ResnetBlock ----
  gn_t_kernel<true><<<NB*32, 256, 0, stream>>>(x, gn1_g, gn1_b, xpb);
  conv3_mfma_kernel<<<dim3(32, NB), 256, 0, stream>>>(xpb, wp1, conv1_b, na, nullptr, buf_h, st2);
  gn_post_kernel<true><<<NB*32, 256, 0, stream>>>(buf_h, st2, gn2_g, gn2_b, xpb);
  gemm_cfunc_kernel<<<dim3(8,2,NB), 256, 0, stream>>>(cp, wcp, cfunc_b, x, buf_h);
  conv3_mfma_kernel<<<dim3(32, NB), 256, 0, stream>>>(xpb, wp2, conv2_b, nullptr, buf_h, buf_h, st3);
  // ---- Attention ----
  gn_post_kernel<false><<<NB*32, 256, 0, stream>>>(buf_h, st3, agn_g, agn_b, xpb);
  gemm_qkv_kernel<<<dim3(8,6,NB), 256, 0, stream>>>(xpb, wqp, qp, kp, vp);
  attn_mfma_kernel<<<256, 1024, 0, stream>>>(qp, kp, vp, op);
  outproj_mfma_kernel<<<dim3(8,2,NB), 256, 0, stream>>>(op, wop, out_b, buf_h, outp);
}

// Round 4
// 344.222 us; speedup vs baseline: 1.0915x; 1.0915x over previous
//
#include <hip/hip_runtime.h>
#include <hip/hip_bf16.h>
#include <math.h>

typedef __hip_bfloat16 bf16;
typedef short short8 __attribute__((ext_vector_type(8)));
typedef float floatx4 __attribute__((ext_vector_type(4)));

#define NB 16
#define NC 256
#define NHW 1024
#define NNE 256
#define NP (NB*NC*NHW)

__device__ __forceinline__ unsigned short f2bu(float f){
  bf16 h = (bf16)f; return *(unsigned short*)&h;
}

// ---------------- GroupNorm two-pass (+Swish) -> packed bf16 x_p[b][cc][px][32] ----------------
template<bool SWISH>
__global__ void gn_t_kernel(const float* __restrict__ src, const float* __restrict__ gamma,
                            const float* __restrict__ beta, short* __restrict__ xp){
  int b = blockIdx.x >> 5, g = blockIdx.x & 31;
  const int GSZ = 8*NHW;
  size_t base = ((size_t)b*NC + g*8)*NHW;
  int tid = threadIdx.x;
  float s = 0.f, ss = 0.f;
  for (int i = tid; i < GSZ; i += 256){
    float v = src[base+i];
    s += v; ss += v*v;
  }
  __shared__ float rs[256], rq[256];
  rs[tid] = s; rq[tid] = ss;
  __syncthreads();
  for (int off=128; off>0; off>>=1){
    if (tid < off){ rs[tid]+=rs[tid+off]; rq[tid]+=rq[tid+off]; }
    __syncthreads();
  }
  float mean = rs[0] * (1.f/GSZ);
  float var  = rq[0] * (1.f/GSZ) - mean*mean;
  float inv  = rsqrtf(var + 1e-5f);
  float gm[8], bt[8];
  #pragma unroll
  for (int j=0;j<8;j++){ gm[j] = gamma[g*8+j]*inv; bt[j] = beta[g*8+j]; }
  short* dst = xp + (((size_t)b*8 + (g>>2))*NHW)*32 + (g&3)*8;
  for (int px = tid; px < NHW; px += 256){
    short8 pk;
    #pragma unroll
    for (int j=0;j<8;j++){
      float v = (src[base + j*NHW + px] - mean)*gm[j] + bt[j];
      if (SWISH) v = v / (1.f + __expf(-v));
      pk[j] = (short)f2bu(v);
    }
    *(short8*)(dst + (size_t)px*32) = pk;
  }
}

// ---------------- GroupNorm single-pass from precomputed stats ----------------
template<bool SWISH>
__global__ void gn_post_kernel(const float* __restrict__ src, const float* __restrict__ st,
                               const float* __restrict__ gamma, const float* __restrict__ beta,
                               short* __restrict__ xp){
  int b = blockIdx.x >> 5, g = blockIdx.x & 31;
  size_t base = ((size_t)b*NC + g*8)*NHW;
  int tid = threadIdx.x;
  float s  = st[(b*32+g)*2+0];
  float ss = st[(b*32+g)*2+1];
  float mean = s * (1.f/8192.f);
  float var  = ss * (1.f/8192.f) - mean*mean;
  float inv  = rsqrtf(var + 1e-5f);
  float gm[8], bt[8];
  #pragma unroll
  for (int j=0;j<8;j++){ gm[j] = gamma[g*8+j]*inv; bt[j] = beta[g*8+j]; }
  short* dst = xp + (((size_t)b*8 + (g>>2))*NHW)*32 + (g&3)*8;
  for (int px = tid; px < NHW; px += 256){
    short8 pk;
    #pragma unroll
    for (int j=0;j<8;j++){
      float v = (src[base + j*NHW + px] - mean)*gm[j] + bt[j];
      if (SWISH) v = v / (1.f + __expf(-v));
      pk[j] = (short)f2bu(v);
    }
    *(short8*)(dst + (size_t)px*32) = pk;
  }
}

// ---------------- conv3 weight prep + stats zero ----------------
__global__ void wprep3_kernel(const float* __restrict__ w1, const float* __restrict__ w2,
                              short* __restrict__ wp1, short* __restrict__ wp2,
                              float* __restrict__ st){
  int co = blockIdx.x & 255;
  const float* w = (blockIdx.x < 256) ? w1 : w2;
  short* wp = (blockIdx.x < 256) ? wp1 : wp2;
  int tid = threadIdx.x;
  if (blockIdx.x == 0){
    for (int i=tid;i<2048;i+=256) st[i] = 0.f;
  }
  __shared__ float tmp[2304];
  for (int i=tid;i<2304;i+=256) tmp[i] = w[(size_t)co*2304 + i];   // [ci][tap]
  __syncthreads();
  for (int j=tid;j<2304;j+=256){
    int tap = j>>8, ci = j&255;
    wp[(((size_t)tap*8 + (ci>>5))*NC + co)*32 + (ci&31)] = (short)f2bu(tmp[ci*9 + tap]);
  }
}

// ---------------- 1x1 weight prep: qkv(768) + cfunc(256) + outw(256) ----------------
__global__ void wprep1_kernel(const float* __restrict__ wq, const float* __restrict__ wc,
                              const float* __restrict__ wo,
                              short* __restrict__ wqp, short* __restrict__ wcp,
                              short* __restrict__ wop){
  int blk = blockIdx.x, tid = threadIdx.x;
  if (blk < 768){
    float v = wq[(size_t)blk*256 + tid];
    wqp[(((size_t)(tid>>5))*768 + blk)*32 + (tid&31)] = (short)f2bu(v);
  } else if (blk < 1024){
    int co = blk - 768;
    float v = wc[(size_t)co*256 + tid];
    wcp[(((size_t)(tid>>5))*256 + co)*32 + (tid&31)] = (short)f2bu(v);
  } else {
    int co = blk - 1024;
    float v = wo[(size_t)co*256 + tid];
    wop[(((size_t)(tid>>5))*256 + co)*32 + (tid&31)] = (short)f2bu(v);
  }
}

// ---------------- c_in fp32 [b][ci][hw] -> cp[b][cc][px][32] bf16 ----------------
__global__ void cvtc_kernel(const float* __restrict__ c_in, short* __restrict__ cp){
  int pxc = blockIdx.x, cc = blockIdx.y, b = blockIdx.z, tid = threadIdx.x;
  __shared__ float ld[32][257];
  size_t gbase = ((size_t)b*NC + cc*32)*NHW + pxc*256;
  for (int j=0;j<32;j++) ld[j][tid] = c_in[gbase + (size_t)j*NHW + tid];
  __syncthreads();
  short* dst = cp + (((size_t)b*8 + cc)*NHW + pxc*256)*32;
  for (int it=0;it<4;it++){
    int pxl = it*64 + (tid>>2), ckl = tid&3;
    short8 pk;
    #pragma unroll
    for (int e=0;e<8;e++) pk[e] = (short)f2bu(ld[ckl*8+e][pxl]);
    *(short8*)(dst + (size_t)pxl*32 + ckl*8) = pk;
  }
}

// ---------------- FeatureWiseAffine bias: na[b][c] ----------------
__global__ void noise_kernel(const float* __restrict__ emb, const float* __restrict__ w,
                             const float* __restrict__ bias, float* __restrict__ na){
  int b = blockIdx.x, c = threadIdx.x;
  __shared__ float e[NNE];
  e[c] = emb[b*NNE + c];
  __syncthreads();
  float acc = bias[c];
  for (int k=0;k<NNE;k++) acc += e[k]*w[c*NNE+k];
  na[b*NC + c] = acc;
}

// ---------------- MFMA conv3x3: 2 output rows/block, 8 waves, j-range split ----------------
// Round-2 geometry (256 blocks, 2-row tiles, same A-traffic) but 8 waves/block:
// wave = (co-slice wslice, half). Halves split the 72 (tap,kk) j-steps 36/36 ->
// 2 independent waves/SIMD cover L2 latency at CONSTANT weight traffic (the r3 mistake
// was doubling traffic). Partial accs combined via LDS fp32 reduction aliased on Xs.
#define XSTR 264
__global__ __launch_bounds__(512,2)
void conv3_mfma_kernel(const short* __restrict__ xp, const short* __restrict__ wp,
                       const float* __restrict__ bias, const float* __restrict__ bias_bc,
                       const float* __restrict__ addf, float* __restrict__ out,
                       float* __restrict__ st){
  const int b = blockIdx.y, y0 = blockIdx.x*2;
  const int tid = threadIdx.x, wave = tid>>6, lane = tid&63;
  const int quad = lane>>4, lm = lane&15;
  const int wslice = wave>>1, half = wave&1;
  __shared__ short Xs[4*34*XSTR];      // 71808 B; rows y0-1..y0+2

  if (tid < 256){ // zero halo columns: 4 rows x 2 sides x 32 chunks
    int r = tid>>6, side = (tid>>5)&1, ck = tid&31;
    short8 z = {0,0,0,0,0,0,0,0};
    *(short8*)&Xs[((r*34) + side*33)*XSTR + ck*8] = z;
  }
  for (int it=0; it<8; ++it){
    int idx = it*512 + tid;
    int r = idx>>10, rem = idx&1023;
    int x = rem>>5, ch = rem&31;       // lanes -> consecutive 16B chunks (conflict-free ds_write)
    int y = y0 - 1 + r;
    short8 v = {0,0,0,0,0,0,0,0};
    if ((unsigned)y < 32u)
      v = *(const short8*)(xp + (((size_t)b*8 + (ch>>2))*NHW + y*32 + x)*32 + (ch&3)*8);
    *(short8*)&Xs[(r*34 + x + 1)*XSTR + ch*8] = v;
  }
  __syncthreads();

  floatx4 acc[4][4];
  #pragma unroll
  for (int mt=0;mt<4;mt++)
    #pragma unroll
    for (int nt=0;nt<4;nt++) acc[mt][nt] = (floatx4){0.f,0.f,0.f,0.f};

  const int co_w = wslice*64;
  const int aoff = (co_w + lm)*32 + quad*8;

  auto ldA = [&](int j, short8 a[4]){
    const short* p = wp + (size_t)j*NC*32 + aoff;
    #pragma unroll
    for (int mt=0;mt<4;mt++) a[mt] = *(const short8*)(p + mt*(16*32));
  };
  auto ldB = [&](int j, short8 bf[4]){
    int tap = j>>3, kk = j&7;
    int dy = (tap*11)>>5;
    int dxp = tap - dy*3;
    int base = (lm+dxp)*XSTR + quad*8 + kk*32 + dy*(34*XSTR);
    #pragma unroll
    for (int nt=0;nt<4;nt++)
      bf[nt] = *(const short8*)&Xs[base + (nt>>1)*(34*XSTR) + (nt&1)*(16*XSTR)];
  };

  const int j0 = half*36, jend = j0 + 35;
  short8 A[4][4], Bf[4][4];
  ldA(j0+0,A[0]); ldB(j0+0,Bf[0]);
  ldA(j0+1,A[1]); ldB(j0+1,Bf[1]);
  ldA(j0+2,A[2]); ldB(j0+2,Bf[2]);
  ldA(j0+3,A[3]); ldB(j0+3,Bf[3]);
  for (int it=j0; it<j0+36; it+=4){
    #pragma unroll
    for (int u=0;u<4;u++){
      __builtin_amdgcn_s_setprio(1);
      #pragma unroll
      for (int mt=0;mt<4;mt++)
        #pragma unroll
        for (int nt=0;nt<4;nt++)
          acc[mt][nt] = __builtin_amdgcn_mfma_f32_16x16x32_bf16(A[u][mt], Bf[u][nt], acc[mt][nt], 0,0,0);
      __builtin_amdgcn_s_setprio(0);
      int j = it + 4 + u; if (j > jend) j = jend;
      ldA(j, A[u]); ldB(j, Bf[u]);
    }
  }

  // ---- cross-half reduction via LDS (Xs dead) ----
  __syncthreads();
  floatx4* red = (floatx4*)Xs;         // 4 wslices x 16 accs x 64 lanes x 16B = 64 KB
  if (half == 1){
    #pragma unroll
    for (int mt=0;mt<4;mt++)
      #pragma unroll
      for (int nt=0;nt<4;nt++)
        red[((wslice*16 + mt*4 + nt)*64) + lane] = acc[mt][nt];
  }
  __syncthreads();
  if (half == 0){
    #pragma unroll
    for (int mt=0;mt<4;mt++)
      #pragma unroll
      for (int nt=0;nt<4;nt++){
        floatx4 o = red[((wslice*16 + mt*4 + nt)*64) + lane];
        acc[mt][nt][0]+=o[0]; acc[mt][nt][1]+=o[1]; acc[mt][nt][2]+=o[2]; acc[mt][nt][3]+=o[3];
      }

    const int hw0 = blockIdx.x*64;
    float gs[4], gq[4];
    #pragma unroll
    for (int mt=0;mt<4;mt++){ gs[mt]=0.f; gq[mt]=0.f; }
    #pragma unroll
    for (int mt=0;mt<4;mt++){
      #pragma unroll
      for (int r=0;r<4;r++){
        int co = co_w + mt*16 + quad*4 + r;
        float bb = bias[co] + (bias_bc ? bias_bc[b*NC + co] : 0.f);
        size_t ob = ((size_t)b*NC + co)*NHW + hw0;
        #pragma unroll
        for (int nt=0;nt<4;nt++){
          size_t oi = ob + nt*16 + lm;
          float v = acc[mt][nt][r] + bb;
          if (addf) v += addf[oi];
          out[oi] = v;
          gs[mt] += v; gq[mt] += v*v;
        }
      }
    }
    #pragma unroll
    for (int mt=0;mt<4;mt++){
      float s = gs[mt], q = gq[mt];
      #pragma unroll
      for (int o=1;o<32;o<<=1){ s += __shfl_xor(s, o, 64); q += __shfl_xor(q, o, 64); }
      if ((lane&31) == 0){
        int g = (co_w>>3) + mt*2 + (quad>>1);
        atomicAdd(&st[(b*32+g)*2+0], s);
        atomicAdd(&st[(b*32+g)*2+1], q);
      }
    }
  }
}

// ---------------- MFMA GEMM: cfunc(c) + bias + x -> fp32 [b][co][hw] ----------------
__global__ __launch_bounds__(256)
void gemm_cfunc_kernel(const short* __restrict__ cp, const short* __restrict__ wcp,
                       const float* __restrict__ bias, const float* __restrict__ xres,
                       float* __restrict__ out){
  const int b = blockIdx.z;
  const int tid = threadIdx.x, wave = tid>>6, lane = tid&63;
  const int quad = lane>>4, lm = lane&15;
  const int M0 = blockIdx.y*128 + (wave>>1)*64;
  const int N0 = blockIdx.x*128 + (wave&1)*64;
  floatx4 acc[4][4];
  #pragma unroll
  for (int mt=0;mt<4;mt++)
    #pragma unroll
    for (int nt=0;nt<4;nt++) acc[mt][nt] = (floatx4){0.f,0.f,0.f,0.f};
  #pragma unroll
  for (int kk=0;kk<8;kk++){
    short8 af[4], bfr[4];
    #pragma unroll
    for (int mt=0;mt<4;mt++)
      af[mt] = *(const short8*)(wcp + ((size_t)kk*256 + M0 + mt*16 + lm)*32 + quad*8);
    #pragma unroll
    for (int nt=0;nt<4;nt++)
      bfr[nt] = *(const short8*)(cp + (((size_t)b*8 + kk)*NHW + N0 + nt*16 + lm)*32 + quad*8);
    #pragma unroll
    for (int mt=0;mt<4;mt++)
      #pragma unroll
      for (int nt=0;nt<4;nt++)
        acc[mt][nt] = __builtin_amdgcn_mfma_f32_16x16x32_bf16(af[mt], bfr[nt], acc[mt][nt], 0,0,0);
  }
  #pragma unroll
  for (int mt=0;mt<4;mt++){
    #pragma unroll
    for (int r=0;r<4;r++){
      int co = M0 + mt*16 + quad*4 + r;
      float bb = bias[co];
      size_t ob = ((size_t)b*NC + co)*NHW + N0;
      #pragma unroll
      for (int nt=0;nt<4;nt++){
        size_t oi = ob + nt*16 + lm;
        out[oi] = acc[mt][nt][r] + bb + xres[oi];
      }
    }
  }
}

// ---------------- MFMA GEMM qkv ----------------
__global__ __launch_bounds__(256)
void gemm_qkv_kernel(const short* __restrict__ ntp, const short* __restrict__ wqp,
                     short* __restrict__ qp, short* __restrict__ kp, short* __restrict__ vp){
  const int b = blockIdx.z;
  const int tid = threadIdx.x, wave = tid>>6, lane = tid&63;
  const int quad = lane>>4, lm = lane&15;
  const int M0 = blockIdx.y*128 + (wave>>1)*64;
  const int N0 = blockIdx.x*128 + (wave&1)*64;
  floatx4 acc[4][4];
  #pragma unroll
  for (int mt=0;mt<4;mt++)
    #pragma unroll
    for (int nt=0;nt<4;nt++) acc[mt][nt] = (floatx4){0.f,0.f,0.f,0.f};
  #pragma unroll
  for (int kk=0;kk<8;kk++){
    short8 af[4], bfr[4];
    #pragma unroll
    for (int mt=0;mt<4;mt++)
      af[mt] = *(const short8*)(wqp + ((size_t)kk*768 + M0 + mt*16 + lm)*32 + quad*8);
    #pragma unroll
    for (int nt=0;nt<4;nt++)
      bfr[nt] = *(const short8*)(ntp + (((size_t)b*8 + kk)*NHW + N0 + nt*16 + lm)*32 + quad*8);
    #pragma unroll
    for (int mt=0;mt<4;mt++)
      #pragma unroll
      for (int nt=0;nt<4;nt++)
        acc[mt][nt] = __builtin_amdgcn_mfma_f32_16x16x32_bf16(af[mt], bfr[nt], acc[mt][nt], 0,0,0);
  }
  #pragma unroll
  for (int mt=0;mt<4;mt++){
    int co_base = M0 + mt*16 + quad*4;
    int sec = co_base >> 8;
    int c = co_base & 255;
    #pragma unroll
    for (int nt=0;nt<4;nt++){
      int s = N0 + nt*16 + lm;
      if (sec < 2){
        unsigned short t0 = f2bu(acc[mt][nt][0]), t1 = f2bu(acc[mt][nt][1]);
        unsigned short t2 = f2bu(acc[mt][nt][2]), t3 = f2bu(acc[mt][nt][3]);
        uint2 w2; w2.x = ((unsigned)t1<<16)|t0; w2.y = ((unsigned)t3<<16)|t2;
        short* dst = (sec==0) ? qp : kp;
        *(uint2*)(dst + (((size_t)b*8 + (c>>5))*NHW + s)*32 + (c&31)) = w2;
      } else {
        #pragma unroll
        for (int r=0;r<4;r++)
          vp[(((size_t)b*32 + (s>>5))*NC + c + r)*32 + (s&31)] = (short)f2bu(acc[mt][nt][r]);
      }
    }
  }
}

// ---------------- MFMA fused attention: 64 q-rows/block, 16 waves, 256 blocks ----------------
__global__ __launch_bounds__(1024)
void attn_mfma_kernel(const short* __restrict__ qp, const short* __restrict__ kp,
                      const short* __restrict__ vp, short* __restrict__ op){
  const int bx = blockIdx.x;
  const int b = bx & 15;               // XCD pin: batches {b,b+8} -> XCD b&7 (32 blocks/XCD)
  const int s0 = (bx >> 4) * 64;
  const int tid = threadIdx.x, wave = tid>>6, lane = tid&63;
  const int quad = lane>>4, lm = lane&15;

  __shared__ short P[64*1024];         // 128 KB, XOR-swizzled granules
  __shared__ float red[64][16];        // reused for max then sum
  __shared__ float fred[64];           // reused for row-max then 1/row-sum

  // ---- phase 1: S = Q K^T ; wave covers rows[0..64) x cols[wave*64 .. +64) ----
  floatx4 sc[4][4];
  #pragma unroll
  for (int rt=0;rt<4;rt++)
    #pragma unroll
    for (int ti=0;ti<4;ti++) sc[rt][ti] = (floatx4){0.f,0.f,0.f,0.f};

  const int colb = wave*64;
  #pragma unroll
  for (int h=0;h<8;h++){
    const size_t hb = ((size_t)b*8 + h)*NHW;
    short8 aq[4], kf[4];
    #pragma unroll
    for (int rt=0;rt<4;rt++)
      aq[rt] = *(const short8*)(qp + (hb + s0 + rt*16 + lm)*32 + quad*8);
    #pragma unroll
    for (int ti=0;ti<4;ti++)
      kf[ti] = *(const short8*)(kp + (hb + colb + ti*16 + lm)*32 + quad*8);
    #pragma unroll
    for (int rt=0;rt<4;rt++)
      #pragma unroll
      for (int ti=0;ti<4;ti++)
        sc[rt][ti] = __builtin_amdgcn_mfma_f32_16x16x32_bf16(aq[rt], kf[ti], sc[rt][ti], 0,0,0);
  }

  // ---- softmax over rows (cols split across 16 waves) ----
  const float scale = 0.0625f;
  float mx[4][4];
  #pragma unroll
  for (int rt=0;rt<4;rt++)
    #pragma unroll
    for (int r=0;r<4;r++) mx[rt][r] = -1e30f;
  #pragma unroll
  for (int rt=0;rt<4;rt++)
    #pragma unroll
    for (int ti=0;ti<4;ti++)
      #pragma unroll
      for (int r=0;r<4;r++){
        float v = sc[rt][ti][r]*scale;
        sc[rt][ti][r] = v;
        mx[rt][r] = fmaxf(mx[rt][r], v);
      }
  #pragma unroll
  for (int o=1;o<16;o<<=1)
    #pragma unroll
    for (int rt=0;rt<4;rt++)
      #pragma unroll
      for (int r=0;r<4;r++) mx[rt][r] = fmaxf(mx[rt][r], __shfl_xor(mx[rt][r], o, 64));
  if (lm==0){
    #pragma unroll
    for (int rt=0;rt<4;rt++)
      #pragma unroll
      for (int r=0;r<4;r++) red[rt*16 + quad*4 + r][wave] = mx[rt][r];
  }
  __syncthreads();
  { // stage-2 max: 16 threads per row
    float v = red[tid>>4][tid&15];
    #pragma unroll
    for (int o=1;o<16;o<<=1) v = fmaxf(v, __shfl_xor(v, o, 64));
    if ((tid&15)==0) fred[tid>>4] = v;
  }
  __syncthreads();
  float fmr[4][4], sm[4][4];
  #pragma unroll
  for (int rt=0;rt<4;rt++)
    #pragma unroll
    for (int r=0;r<4;r++){ fmr[rt][r] = fred[rt*16 + quad*4 + r]; sm[rt][r] = 0.f; }
  #pragma unroll
  for (int rt=0;rt<4;rt++)
    #pragma unroll
    for (int ti=0;ti<4;ti++)
      #pragma unroll
      for (int r=0;r<4;r++){
        float e = __expf(sc[rt][ti][r] - fmr[rt][r]);
        sc[rt][ti][r] = e;
        sm[rt][r] += e;
      }
  #pragma unroll
  for (int o=1;o<16;o<<=1)
    #pragma unroll
    for (int rt=0;rt<4;rt++)
      #pragma unroll
      for (int r=0;r<4;r++) sm[rt][r] += __shfl_xor(sm[rt][r], o, 64);
  __syncthreads();   // red[] (max partials) dead -> safe to reuse for sums
  if (lm==0){
    #pragma unroll
    for (int rt=0;rt<4;rt++)
      #pragma unroll
      for (int r=0;r<4;r++) red[rt*16 + quad*4 + r][wave] = sm[rt][r];
  }
  __syncthreads();
  { // stage-2 sum -> 1/sum
    float v = red[tid>>4][tid&15];
    #pragma unroll
    for (int o=1;o<16;o<<=1) v += __shfl_xor(v, o, 64);
    if ((tid&15)==0) fred[tid>>4] = 1.f/v;
  }
  __syncthreads();
  float fir[4][4];
  #pragma unroll
  for (int rt=0;rt<4;rt++)
    #pragma unroll
    for (int r=0;r<4;r++) fir[rt][r] = fred[rt*16 + quad*4 + r];
  // write P normalized, swizzled: elem(row,col) at row*1024 + ((col>>3 ^ row&7)<<3) + (col&7)
  #pragma unroll
  for (int rt=0;rt<4;rt++)
    #pragma unroll
    for (int ti=0;ti<4;ti++)
      #pragma unroll
      for (int r=0;r<4;r++){
        int row = rt*16 + quad*4 + r;
        int col = colb + ti*16 + lm;
        int off = row*1024 + ((((col>>3) ^ (row&7))&127)<<3) + (col&7);
        P[off] = (short)f2bu(sc[rt][ti][r]*fir[rt][r]);
      }
  __syncthreads();

  // ---- phase 2: O = P V^T ; wave = (cg: 32 ch, sh: 32 s) ----
  const int cg = wave>>1, sh = wave&1;
  const int ch0 = cg*32;
  floatx4 oacc[2][2];
  #pragma unroll
  for (int mt=0;mt<2;mt++)
    #pragma unroll
    for (int nt=0;nt<2;nt++) oacc[mt][nt] = (floatx4){0.f,0.f,0.f,0.f};

  #pragma unroll
  for (int kk=0;kk<32;kk++){
    short8 pf[2], vf[2];
    #pragma unroll
    for (int mt=0;mt<2;mt++){
      int row = sh*32 + mt*16 + lm;
      int off = row*1024 + ((((kk*4 + quad) ^ (row&7))&127)<<3);
      pf[mt] = *(const short8*)(&P[off]);
    }
    #pragma unroll
    for (int nt=0;nt<2;nt++)
      vf[nt] = *(const short8*)(vp + (((size_t)b*32 + kk)*NC + ch0 + nt*16 + lm)*32 + quad*8);
    #pragma unroll
    for (int mt=0;mt<2;mt++)
      #pragma unroll
      for (int nt=0;nt<2;nt++)
        oacc[mt][nt] = __builtin_amdgcn_mfma_f32_16x16x32_bf16(pf[mt], vf[nt], oacc[mt][nt], 0,0,0);
  }

  // packed bf16 epilogue: o_p[b][cc][s][32]
  #pragma unroll
  for (int nt=0;nt<2;nt++){
    int c = ch0 + nt*16 + lm;
    int cc = c>>5, cl = c&31;
    #pragma unroll
    for (int mt=0;mt<2;mt++)
      #pragma unroll
      for (int r=0;r<4;r++){
        int s = s0 + sh*32 + mt*16 + quad*4 + r;
        op[(((size_t)b*8 + cc)*NHW + s)*32 + cl] = (short)f2bu(oacc[mt][nt][r]);
      }
  }
}

// ---------------- MFMA out-proj: out = W@o + out_b + h ----------------
__global__ __launch_bounds__(256)
void outproj_mfma_kernel(const short* __restrict__ op, const short* __restrict__ wop,
                         const float* __restrict__ obias, const float* __restrict__ h,
                         float* __restrict__ out){
  const int b = blockIdx.z;
  const int tid = threadIdx.x, wave = tid>>6, lane = tid&63;
  const int quad = lane>>4, lm = lane&15;
  const int M0 = blockIdx.y*128 + (wave>>1)*64;
  const int N0 = blockIdx.x*128 + (wave&1)*64;
  floatx4 acc[4][4];
  #pragma unroll
  for (int mt=0;mt<4;mt++)
    #pragma unroll
    for (int nt=0;nt<4;nt++) acc[mt][nt] = (floatx4){0.f,0.f,0.f,0.f};
  #pragma unroll
  for (int kk=0;kk<8;kk++){
    short8 af[4], bfr[4];
    #pragma unroll
    for (int mt=0;mt<4;mt++)
      af[mt] = *(const short8*)(wop + ((size_t)kk*256 + M0 + mt*16 + lm)*32 + quad*8);
    #pragma unroll
    for (int nt=0;nt<4;nt++)
      bfr[nt] = *(const short8*)(op + (((size_t)b*8 + kk)*NHW + N0 + nt*16 + lm)*32 + quad*8);
    #pragma unroll
    for (int mt=0;mt<4;mt++)
      #pragma unroll
      for (int nt=0;nt<4;nt++)
        acc[mt][nt] = __builtin_amdgcn_mfma_f32_16x16x32_bf16(af[mt], bfr[nt], acc[mt][nt], 0,0,0);
  }
  #pragma unroll
  for (int mt=0;mt<4;mt++){
    #pragma unroll
    for (int r=0;r<4;r++){
      int co = M0 + mt*16 + quad*4 + r;
      float bb = obias[co];
      size_t ob = ((size_t)b*NC + co)*NHW + N0;
      #pragma unroll
      for (int nt=0;nt<4;nt++){
        size_t oi = ob + nt*16 + lm;
        out[oi] = acc[mt][nt][r] + bb + h[oi];
      }
    }
  }
}

extern "C" void kernel_launch(void* const* d_in, const int* in_sizes, int n_in,
                              void* d_out, int out_size, void* d_ws, size_t ws_size,
                              hipStream_t stream){
  const float* x        = (const float*)d_in[0];
  const float* time_emb = (const float*)d_in[1];
  const float* c_in     = (const float*)d_in[2];
  const float* gn1_g    = (const float*)d_in[3];
  const float* gn1_b    = (const float*)d_in[4];
  const float* conv1_w  = (const float*)d_in[5];
  const float* conv1_b  = (const float*)d_in[6];
  const float* noise_w  = (const float*)d_in[7];
  const float* noise_b  = (const float*)d_in[8];
  const float* gn2_g    = (const float*)d_in[9];
  const float* gn2_b    = (const float*)d_in[10];
  const float* conv2_w  = (const float*)d_in[11];
  const float* conv2_b  = (const float*)d_in[12];
  const float* cfunc_w  = (const float*)d_in[13];
  const float* cfunc_b  = (const float*)d_in[14];
  const float* agn_g    = (const float*)d_in[15];
  const float* agn_b    = (const float*)d_in[16];
  const float* qkv_w    = (const float*)d_in[17];
  const float* out_w    = (const float*)d_in[18];
  const float* out_b    = (const float*)d_in[19];
  float* outp = (float*)d_out;

  // ---- workspace layout (~67 MB) ----
  float* ws = (float*)d_ws;
  float* buf_h = ws;                       // NP fp32
  float* buf_t = buf_h + NP;               // NP fp32 (early: cp bf16 alias; late: o_p bf16 alias)
  short* xpb   = (short*)(buf_t + NP);     // NP bf16
  short* qp    = xpb + NP;                 // NP bf16
  short* kp    = qp + NP;                  // NP bf16
  short* vp    = kp + NP;                  // NP bf16
  short* wp1   = vp + NP;                  // 589824
  short* wp2   = wp1 + 589824;             // 589824
  short* wqp   = wp2 + 589824;             // 196608
  short* wcp   = wqp + 196608;             // 65536
  short* wop   = wcp + 65536;              // 65536
  float* na    = (float*)(wop + 65536);    // NB*NC
  float* st    = na + NB*NC;               // 2048 floats
  float* st2   = st;
  float* st3   = st + 1024;
  short* cp    = (short*)buf_t;            // alias (dead after gemm_cfunc)
  short* op    = (short*)buf_t;            // alias (written by attn after cp dead)

  // ---- prep ----
  wprep3_kernel<<<512, 256, 0, stream>>>(conv1_w, conv2_w, wp1, wp2, st);
  wprep1_kernel<<<1280, 256, 0, stream>>>(qkv_w, cfunc_w, out_w, wqp, wcp, wop);
  cvtc_kernel<<<dim3(4,8,NB), 256, 0, stream>>>(c_in, cp);
  noise_kernel<<<NB, 256, 0, stream>>>(time_emb, noise_w, noise_b, na);
  // ---- ResnetBlock ----
  gn_t_kernel<true><<<NB*32, 256, 0, stream>>>(x, gn1_g, gn1_b, xpb);
  conv3_mfma_kernel<<<dim3(16, NB), 512, 0, stream>>>(xpb, wp1, conv1_b, na, nullptr, buf_h, st2);
  gn_post_kernel<true><<<NB*32, 256, 0, stream>>>(buf_h, st2, gn2_g, gn2_b, xpb);
  gemm_cfunc_kernel<<<dim3(8,2,NB), 256, 0, stream>>>(cp, wcp, cfunc_b, x, buf_h);
  conv3_mfma_kernel<<<dim3(16, NB), 512, 0, stream>>>(xpb, wp2, conv2_b, nullptr, buf_h, buf_h, st3);
  // ---- Attention ----
  gn_post_kernel<false><<<NB*32, 256, 0, stream>>>(buf_h, st3, agn_g, agn_b, xpb);
  gemm_qkv_kernel<<<dim3(8,6,NB), 256, 0, stream>>>(xpb, wqp, qp, kp, vp);
  attn_mfma_kernel<<<256, 1024, 0, stream>>>(qp, kp, vp, op);
  outproj_mfma_kernel<<<dim3(8,2,NB), 256, 0, stream>>>(op, wop, out_b, buf_h, outp);
}